// Round 1
// baseline (4347.915 us; speedup 1.0000x reference)
//
#include <hip/hip_runtime.h>

typedef __bf16 bf16;
typedef __bf16 bf16x8 __attribute__((ext_vector_type(8)));
typedef float  f32x16 __attribute__((ext_vector_type(16)));

#define MFMA(a, b, c) __builtin_amdgcn_mfma_f32_32x32x16_bf16((a), (b), (c), 0, 0, 0)

#define BSZ  2048
#define H    256
#define NOUT 5

// packed weight buffer, units of bf16x8 fragments (16B each)
// frag index layout for big mats: (tile*16 + ks)*64 + lane
#define F_WHH1 0            // 24*16*64 = 24576 frags
#define F_WIH2 24576
#define F_WHH2 49152
#define F_WIH1 73728        // 24*64 frags (single padded K-step, K=8 real)
#define F_LIN  75264        // 16*64 frags (N padded 5->32)
#define F_TOTAL 76288

__device__ bf16x8 g_pk[F_TOTAL];

__global__ void prepack_kernel(const float* __restrict__ wih1,
                               const float* __restrict__ whh1,
                               const float* __restrict__ wih2,
                               const float* __restrict__ whh2,
                               const float* __restrict__ lin_w) {
  int fid = blockIdx.x * 256 + threadIdx.x;
  if (fid >= F_TOTAL) return;
  bf16x8 v;
  if (fid < F_WIH1) {
    const float* W = (fid < F_WIH2) ? whh1 : (fid < F_WHH2) ? wih2 : whh2;
    int r    = fid % 24576;
    int tile = r >> 10;        // /(16*64)
    int ks   = (r >> 6) & 15;
    int lane = r & 63;
    int n = tile * 32 + (lane & 31);
    int k = ks * 16 + (lane >> 5) * 8;
    const float* p = W + n * 256 + k;
#pragma unroll
    for (int i = 0; i < 8; ++i) v[i] = (bf16)p[i];
  } else if (fid < F_LIN) {
    int r    = fid - F_WIH1;
    int tile = r >> 6;
    int lane = r & 63;
    int n  = tile * 32 + (lane & 31);
    int k0 = (lane >> 5) * 8;
#pragma unroll
    for (int i = 0; i < 8; ++i) {
      int kk = k0 + i;
      v[i] = (kk < 8) ? (bf16)wih1[n * 8 + kk] : (bf16)0.f;
    }
  } else {
    int r    = fid - F_LIN;
    int ks   = r >> 6;
    int lane = r & 63;
    int n = lane & 31;
    int k = ks * 16 + (lane >> 5) * 8;
#pragma unroll
    for (int i = 0; i < 8; ++i)
      v[i] = (n < NOUT) ? (bf16)lin_w[n * 256 + k + i] : (bf16)0.f;
  }
  g_pk[fid] = v;
}

__device__ __forceinline__ float sigmoidf_(float x) { return 1.f / (1.f + __expf(-x)); }
__device__ __forceinline__ float tanhf_(float x) {
  float e = __expf(-2.f * x);
  return (1.f - e) / (1.f + e);
}

// Each block owns 32 batch rows for all T steps. 8 waves; wave w owns h-dims
// [32w, 32w+31] (MFMA N-tiles {w, w+8, w+16} = r/z/n gate rows).
// h master state: fp32 registers in MFMA C/D layout; bf16 shadow in LDS
// (double-buffered, XOR-swizzled on 16B units: elem (m,j) at
//  m*256 + ((j>>3)^m)*8 + (j&7)) for A-fragment ds_read_b128.
__global__ __launch_bounds__(512, 2) void gru_kernel(
    const int* __restrict__ plen_p,
    const float* __restrict__ rnn_in,
    const float* __restrict__ out0,
    const float* __restrict__ h01,
    const float* __restrict__ h02,
    const float* __restrict__ bih1, const float* __restrict__ bhh1,
    const float* __restrict__ bih2, const float* __restrict__ bhh2,
    const float* __restrict__ lin_b,
    float* __restrict__ out) {
  __shared__ bf16 h1s[2][32 * 256];
  __shared__ bf16 h2s[2][32 * 256];
  __shared__ bf16 xs[32 * 16];

  const int T   = plen_p[0];
  const int tid = threadIdx.x;
  const int w   = tid >> 6;
  const int l   = tid & 63;
  const int col = l & 31;
  const int hv  = l >> 5;
  const int b0  = blockIdx.x * 32;
  const int jd  = w * 32 + col;   // this lane's h-dim / gate column

  // per-lane biases (uniform across the two lane-halves)
  float br1 = bih1[jd] + bhh1[jd];
  float bz1 = bih1[H + jd] + bhh1[H + jd];
  float bi1 = bih1[2 * H + jd];
  float bh1 = bhh1[2 * H + jd];
  float br2 = bih2[jd] + bhh2[jd];
  float bz2 = bih2[H + jd] + bhh2[H + jd];
  float bi2 = bih2[2 * H + jd];
  float bh2 = bhh2[2 * H + jd];
  float lb  = (col < NOUT) ? lin_b[col] : 0.f;

  // fp32 master h state in C/D layout: reg q -> row (q&3)+8*(q>>2)+4*hv, col jd
  float h1r[16], h2r[16];
#pragma unroll
  for (int q = 0; q < 16; ++q) {
    int m  = (q & 3) + 8 * (q >> 2) + 4 * hv;
    h1r[q] = h01[(b0 + m) * H + jd];
    h2r[q] = h02[(b0 + m) * H + jd];
  }

  // LDS init: bf16 shadows (swizzled), x tile
  for (int idx = tid; idx < 32 * 32; idx += 512) {
    int m = idx >> 5, u = idx & 31;
    const float* p1 = h01 + (b0 + m) * H + u * 8;
    const float* p2 = h02 + (b0 + m) * H + u * 8;
    bf16x8 v1, v2;
#pragma unroll
    for (int i = 0; i < 8; ++i) { v1[i] = (bf16)p1[i]; v2[i] = (bf16)p2[i]; }
    *(bf16x8*)&h1s[0][m * 256 + ((u ^ m) << 3)] = v1;
    *(bf16x8*)&h2s[0][m * 256 + ((u ^ m) << 3)] = v2;
  }
  if (tid < 256) {  // zero pad cols 8..15
    int m = tid >> 3, c = 8 + (tid & 7);
    xs[m * 16 + c] = (bf16)0.f;
  }
  if (tid < 160) {  // out0 -> cols 0..4
    int m = tid / 5, o = tid % 5;
    xs[m * 16 + o] = (bf16)out0[(b0 + m) * NOUT + o];
  }
  if (tid >= 256 && tid < 352) {  // u(0) -> cols 5..7
    int r = tid - 256; int m = r / 3, c = r % 3;
    xs[m * 16 + 5 + c] = (bf16)rnn_in[(b0 + m) * 4 + c];
  }
  __syncthreads();

  const int am = col;  // A-fragment row for this lane
  int cur = 0;

  for (int t = 0; t < T; ++t) {
    const bf16* h1c = h1s[cur];
    const bf16* h2c = h2s[cur];
    bf16* h1n = h1s[cur ^ 1];
    bf16* h2n = h2s[cur ^ 1];

    // ================= layer 1 =================
    f32x16 ar, az, ahn, ain;
#pragma unroll
    for (int i = 0; i < 16; ++i) { ar[i] = 0.f; az[i] = 0.f; ahn[i] = 0.f; ain[i] = 0.f; }
    {
      const bf16x8* pr = g_pk + F_WHH1 + (w     ) * 1024 + l;
      const bf16x8* pz = g_pk + F_WHH1 + (w +  8) * 1024 + l;
      const bf16x8* pn = g_pk + F_WHH1 + (w + 16) * 1024 + l;
#pragma unroll 4
      for (int ks = 0; ks < 16; ++ks) {
        bf16x8 a = *(const bf16x8*)&h1c[am * 256 + (((2 * ks + hv) ^ am) << 3)];
        ar  = MFMA(a, pr[ks * 64], ar);
        az  = MFMA(a, pz[ks * 64], az);
        ahn = MFMA(a, pn[ks * 64], ahn);
      }
      bf16x8 ax = *(const bf16x8*)&xs[am * 16 + hv * 8];
      ar  = MFMA(ax, g_pk[F_WIH1 + (w     ) * 64 + l], ar);
      az  = MFMA(ax, g_pk[F_WIH1 + (w +  8) * 64 + l], az);
      ain = MFMA(ax, g_pk[F_WIH1 + (w + 16) * 64 + l], ain);
    }
#pragma unroll
    for (int q = 0; q < 16; ++q) {
      float r = sigmoidf_(ar[q] + br1);
      float z = sigmoidf_(az[q] + bz1);
      float n = tanhf_(ain[q] + bi1 + r * (ahn[q] + bh1));
      float h = (1.f - z) * n + z * h1r[q];
      h1r[q]  = h;
      int m = (q & 3) + 8 * (q >> 2) + 4 * hv;
      h1n[m * 256 + (((jd >> 3) ^ m) << 3) + (jd & 7)] = (bf16)h;
    }
    __syncthreads();

    // ================= layer 2 =================
#pragma unroll
    for (int i = 0; i < 16; ++i) { ar[i] = 0.f; az[i] = 0.f; ahn[i] = 0.f; ain[i] = 0.f; }
    {
      const bf16x8* pr = g_pk + F_WIH2 + (w     ) * 1024 + l;
      const bf16x8* pz = g_pk + F_WIH2 + (w +  8) * 1024 + l;
      const bf16x8* pn = g_pk + F_WIH2 + (w + 16) * 1024 + l;
#pragma unroll 4
      for (int ks = 0; ks < 16; ++ks) {
        bf16x8 a = *(const bf16x8*)&h1n[am * 256 + (((2 * ks + hv) ^ am) << 3)];
        ar  = MFMA(a, pr[ks * 64], ar);
        az  = MFMA(a, pz[ks * 64], az);
        ain = MFMA(a, pn[ks * 64], ain);
      }
    }
    {
      const bf16x8* pr = g_pk + F_WHH2 + (w     ) * 1024 + l;
      const bf16x8* pz = g_pk + F_WHH2 + (w +  8) * 1024 + l;
      const bf16x8* pn = g_pk + F_WHH2 + (w + 16) * 1024 + l;
#pragma unroll 4
      for (int ks = 0; ks < 16; ++ks) {
        bf16x8 a = *(const bf16x8*)&h2c[am * 256 + (((2 * ks + hv) ^ am) << 3)];
        ar  = MFMA(a, pr[ks * 64], ar);
        az  = MFMA(a, pz[ks * 64], az);
        ahn = MFMA(a, pn[ks * 64], ahn);
      }
    }
#pragma unroll
    for (int q = 0; q < 16; ++q) {
      float r = sigmoidf_(ar[q] + br2);
      float z = sigmoidf_(az[q] + bz2);
      float n = tanhf_(ain[q] + bi2 + r * (ahn[q] + bh2));
      float h = (1.f - z) * n + z * h2r[q];
      h2r[q]  = h;
      int m = (q & 3) + 8 * (q >> 2) + 4 * hv;
      h2n[m * 256 + (((jd >> 3) ^ m) << 3) + (jd & 7)] = (bf16)h;
    }
    __syncthreads();

    // ================= output head + next-step x =================
    if (w == 0) {
      f32x16 ao;
#pragma unroll
      for (int i = 0; i < 16; ++i) ao[i] = 0.f;
      const bf16x8* po = g_pk + F_LIN + l;
#pragma unroll 4
      for (int ks = 0; ks < 16; ++ks) {
        bf16x8 a = *(const bf16x8*)&h2n[am * 256 + (((2 * ks + hv) ^ am) << 3)];
        ao = MFMA(a, po[ks * 64], ao);
      }
      if (col < NOUT) {
#pragma unroll
        for (int q = 0; q < 16; ++q) {
          int m   = (q & 3) + 8 * (q >> 2) + 4 * hv;
          float v = ao[q] + lb;
          out[((size_t)(b0 + m) * T + t) * NOUT + col] = v;
          xs[m * 16 + col] = (bf16)v;
        }
      }
    }
    if (w == 1 && t + 1 < T) {
      for (int j = l; j < 96; j += 64) {
        int m = j / 3, c = j % 3;
        xs[m * 16 + 5 + c] = (bf16)rnn_in[((size_t)(t + 1) * BSZ + b0 + m) * 4 + c];
      }
    }
    __syncthreads();
    cur ^= 1;
  }
}

extern "C" void kernel_launch(void* const* d_in, const int* in_sizes, int n_in,
                              void* d_out, int out_size, void* d_ws, size_t ws_size,
                              hipStream_t stream) {
  const int*   plen  = (const int*)d_in[0];
  const float* rnn   = (const float*)d_in[1];
  const float* out0  = (const float*)d_in[2];
  const float* h01   = (const float*)d_in[3];
  const float* h02   = (const float*)d_in[4];
  const float* wih1  = (const float*)d_in[5];
  const float* whh1  = (const float*)d_in[6];
  const float* bih1  = (const float*)d_in[7];
  const float* bhh1  = (const float*)d_in[8];
  const float* wih2  = (const float*)d_in[9];
  const float* whh2  = (const float*)d_in[10];
  const float* bih2  = (const float*)d_in[11];
  const float* bhh2  = (const float*)d_in[12];
  const float* lin_w = (const float*)d_in[13];
  const float* lin_b = (const float*)d_in[14];

  prepack_kernel<<<(F_TOTAL + 255) / 256, 256, 0, stream>>>(wih1, whh1, wih2, whh2, lin_w);
  gru_kernel<<<BSZ / 32, 512, 0, stream>>>(plen, rnn, out0, h01, h02,
                                           bih1, bhh1, bih2, bhh2, lin_b,
                                           (float*)d_out);
}